// Round 3
// baseline (111.481 us; speedup 1.0000x reference)
//
#include <hip/hip_runtime.h>
#include <stdint.h>

// KeepTopN: inputs (32, 56, 56, 256) f32, n = 48 (k-th largest per row).
// Strategy: speculative compaction with analytic threshold T=3.0 (data is
// N(0,1); E[candidates/row] ~= 1084 >> 48), exact radix-select on candidates,
// guarded exact fallback (never triggered on this data), then mask pass.
#define ROWS 32
#define ROW_LEN 802816      // 56*56*256
#define ROW_LEN4 200704     // ROW_LEN / 4
#define BPR 98              // blocks per row (200704 = 98 * 2048)
#define F4_PER_BLOCK 2048
#define THREADS 256
#define F4_PER_THREAD 8     // 2048 / 256
#define TG 3.0f             // speculative threshold (analytic, data-independent)
#define BCAP 40             // per-block candidate slots (E~11, P(>40) ~ 1e-10)
#define CAP_ROW (BPR * BCAP)  // 3920

// ws layout (bytes), total 514560 (previous rounds used 525KB OK):
//   cand : u32[ROWS][BPR][BCAP] @ 0       (501760)
//   bcnt : i32[ROWS][BPR]       @ 501760  (12544)   always fully rewritten
//   thr  : f32[ROWS]            @ 514304  (128)
//   flag : i32[ROWS]            @ 514432  (128)     always fully rewritten
#define OFF_BCNT 501760
#define OFF_THR  514304
#define OFF_FLAG 514432

// Monotone order-preserving f32 -> u32 key (larger float -> larger key).
__device__ __forceinline__ uint32_t fkey(float x) {
    uint32_t u = __float_as_uint(x);
    return (u & 0x80000000u) ? ~u : (u | 0x80000000u);
}
__device__ __forceinline__ float fkey_inv(uint32_t k) {
    uint32_t u = (k & 0x80000000u) ? (k & 0x7FFFFFFFu) : ~k;
    return __uint_as_float(u);
}

// Pass 1: streaming read; compact values > TG into this block's private slots.
// No global atomics, no pre-zeroing (bcnt always written).
__global__ __launch_bounds__(THREADS) void k_spec(const float* __restrict__ in,
                                                  uint32_t* __restrict__ cand,
                                                  int* __restrict__ bcnt) {
    __shared__ uint32_t lc[BCAP];
    __shared__ int lcnt;
    const int row = blockIdx.x / BPR;
    const int blk = blockIdx.x % BPR;
    if (threadIdx.x == 0) lcnt = 0;
    __syncthreads();
    const float4* p = (const float4*)in + (size_t)row * ROW_LEN4
                      + (size_t)blk * F4_PER_BLOCK + threadIdx.x;
#pragma unroll
    for (int v = 0; v < F4_PER_THREAD; ++v) {
        float4 d = p[v * THREADS];
        if (d.x > TG) { int q = atomicAdd(&lcnt, 1); if (q < BCAP) lc[q] = fkey(d.x); }
        if (d.y > TG) { int q = atomicAdd(&lcnt, 1); if (q < BCAP) lc[q] = fkey(d.y); }
        if (d.z > TG) { int q = atomicAdd(&lcnt, 1); if (q < BCAP) lc[q] = fkey(d.z); }
        if (d.w > TG) { int q = atomicAdd(&lcnt, 1); if (q < BCAP) lc[q] = fkey(d.w); }
    }
    __syncthreads();
    const int c = lcnt;
    if (threadIdx.x == 0) bcnt[row * BPR + blk] = c;  // raw count (overflow detected later)
    const int cc = c < BCAP ? c : BCAP;
    for (int i = threadIdx.x; i < cc; i += THREADS)
        cand[((size_t)row * BPR + blk) * BCAP + i] = lc[i];
}

// Pass 2: per row, gather candidates to LDS, exact 4x8-bit radix select of the
// n-th largest. Sets flag=1 + thr on success; flag=0 -> fallback handles row.
__global__ __launch_bounds__(THREADS) void k_sel(const int* __restrict__ n_ptr,
                                                 const int* __restrict__ bcnt,
                                                 const uint32_t* __restrict__ cand,
                                                 float* __restrict__ thr,
                                                 int* __restrict__ flag) {
    __shared__ uint32_t keys[CAP_ROW];
    __shared__ int offs[BPR + 1];
    __shared__ uint32_t h[256];
    __shared__ int sel_s, rank_s, ok_s;
    const int row = blockIdx.x;
    const int n = *n_ptr;

    if (threadIdx.x == 0) {
        int s = 0, ok = 1;
        for (int b = 0; b < BPR; ++b) {
            offs[b] = s;
            int c = bcnt[row * BPR + b];
            if (c > BCAP) ok = 0;           // per-block overflow -> fallback
            s += (c < BCAP ? c : BCAP);
        }
        offs[BPR] = s;
        ok_s = (ok && s >= n && n >= 1) ? 1 : 0;  // candidates cover top-n?
    }
    __syncthreads();
    const int m = offs[BPR];
    if (!ok_s) { if (threadIdx.x == 0) flag[row] = 0; return; }

    // coalesced-ish gather: iterate slot space, keep occupied slots
    for (int i = threadIdx.x; i < CAP_ROW; i += THREADS) {
        const int b = i / BCAP, j = i % BCAP;
        const int c = offs[b + 1] - offs[b];
        if (j < c) keys[offs[b] + j] = cand[((size_t)row * BPR + b) * BCAP + j];
    }
    __syncthreads();

    uint32_t prefix = 0, mask = 0;
    int r = n;  // rank from largest, 1-indexed
    for (int rd = 0; rd < 4; ++rd) {
        const int sh = 24 - rd * 8;
        for (int i = threadIdx.x; i < 256; i += THREADS) h[i] = 0;
        __syncthreads();
        for (int i = threadIdx.x; i < m; i += THREADS) {
            const uint32_t k = keys[i];
            if ((k & mask) == prefix) atomicAdd(&h[(k >> sh) & 255u], 1u);
        }
        __syncthreads();
        if (threadIdx.x == 0) {
            uint32_t cum = 0; int v = 0;
            for (int d = 255; d >= 0; --d) {
                const uint32_t c = h[d];
                if ((int)(cum + c) >= r) { v = d; rank_s = r - (int)cum; break; }
                cum += c;
            }
            sel_s = v;
        }
        __syncthreads();
        prefix |= ((uint32_t)sel_s) << sh;
        mask |= 255u << sh;
        r = rank_s;
        __syncthreads();
    }
    if (threadIdx.x == 0) {
        thr[row] = fkey_inv(prefix);
        flag[row] = 1;
    }
}

// Exact fallback: per-row radix select over the full row from global memory.
// Early-exits when flag==1 (always, for this data). Unconditionally correct.
__global__ __launch_bounds__(THREADS) void k_fallback(const float* __restrict__ in,
                                                      const int* __restrict__ n_ptr,
                                                      const int* __restrict__ flag,
                                                      float* __restrict__ thr) {
    const int row = blockIdx.x;
    if (flag[row]) return;
    __shared__ uint32_t h[2048];
    __shared__ int sel_s, rank_s;
    const int n = *n_ptr;
    uint32_t prefix = 0, mask = 0;
    int r = (n < 1) ? 1 : n;
    const int sh_arr[4] = {21, 13, 5, 0};
    const int W_arr[4] = {2048, 256, 256, 32};
    const float4* p = (const float4*)in + (size_t)row * ROW_LEN4;
    for (int rd = 0; rd < 4; ++rd) {
        const int sh = sh_arr[rd], W = W_arr[rd];
        for (int i = threadIdx.x; i < W; i += THREADS) h[i] = 0;
        __syncthreads();
        for (int i = threadIdx.x; i < ROW_LEN4; i += THREADS) {
            const float4 d = p[i];
            uint32_t k;
            k = fkey(d.x); if ((k & mask) == prefix) atomicAdd(&h[(k >> sh) & (uint32_t)(W - 1)], 1u);
            k = fkey(d.y); if ((k & mask) == prefix) atomicAdd(&h[(k >> sh) & (uint32_t)(W - 1)], 1u);
            k = fkey(d.z); if ((k & mask) == prefix) atomicAdd(&h[(k >> sh) & (uint32_t)(W - 1)], 1u);
            k = fkey(d.w); if ((k & mask) == prefix) atomicAdd(&h[(k >> sh) & (uint32_t)(W - 1)], 1u);
        }
        __syncthreads();
        if (threadIdx.x == 0) {
            uint32_t cum = 0; int v = 0;
            for (int d = W - 1; d >= 0; --d) {
                const uint32_t c = h[d];
                if ((int)(cum + c) >= r) { v = d; rank_s = r - (int)cum; break; }
                cum += c;
            }
            sel_s = v;
        }
        __syncthreads();
        prefix |= ((uint32_t)sel_s) << sh;
        mask |= (uint32_t)(W - 1) << sh;
        r = rank_s;
        __syncthreads();
    }
    if (threadIdx.x == 0) thr[row] = fkey_inv(prefix);
}

__global__ __launch_bounds__(THREADS) void k_mask(const float* __restrict__ in,
                                                  const float* __restrict__ thr,
                                                  float* __restrict__ out) {
    const int row = blockIdx.x / BPR;
    const int blk = blockIdx.x % BPR;
    const float t = thr[row];
    const size_t base = (size_t)row * ROW_LEN4 + (size_t)blk * F4_PER_BLOCK + threadIdx.x;
    const float4* p = (const float4*)in + base;
    float4* q = (float4*)out + base;
#pragma unroll
    for (int v = 0; v < F4_PER_THREAD; ++v) {
        float4 d = p[v * THREADS];
        d.x = (d.x >= t) ? d.x : 0.0f;
        d.y = (d.y >= t) ? d.y : 0.0f;
        d.z = (d.z >= t) ? d.z : 0.0f;
        d.w = (d.w >= t) ? d.w : 0.0f;
        q[v * THREADS] = d;
    }
}

extern "C" void kernel_launch(void* const* d_in, const int* in_sizes, int n_in,
                              void* d_out, int out_size, void* d_ws, size_t ws_size,
                              hipStream_t stream) {
    const float* in = (const float*)d_in[0];
    const int* n_ptr = (const int*)d_in[1];
    float* out = (float*)d_out;
    char* ws = (char*)d_ws;

    uint32_t* cand = (uint32_t*)ws;
    int* bcnt = (int*)(ws + OFF_BCNT);
    float* thr = (float*)(ws + OFF_THR);
    int* flag = (int*)(ws + OFF_FLAG);

    k_spec<<<ROWS * BPR, THREADS, 0, stream>>>(in, cand, bcnt);
    k_sel<<<ROWS, THREADS, 0, stream>>>(n_ptr, bcnt, cand, thr, flag);
    k_fallback<<<ROWS, THREADS, 0, stream>>>(in, n_ptr, flag, thr);
    k_mask<<<ROWS * BPR, THREADS, 0, stream>>>(in, thr, out);
}

// Round 4
// 55.052 us; speedup vs baseline: 2.0250x; 2.0250x over previous
//
#include <hip/hip_runtime.h>
#include <stdint.h>

// KeepTopN: inputs (32, 56, 56, 256) f32, n = 48 (k-th largest per row).
// Speculative compaction (T=3.0 analytic; data ~ N(0,1), E[cand/row]~=1084),
// fully-parallel exact radix select on candidates (registers + LDS suffix
// scan), inlined exact fallback (never taken on this data), mask pass.
#define ROWS 32
#define ROW_LEN 802816      // 56*56*256
#define ROW_LEN4 200704     // ROW_LEN / 4
#define BPR 98              // blocks per row (200704 = 98 * 2048)
#define F4_PER_BLOCK 2048
#define THREADS 256
#define F4_PER_THREAD 8     // 2048 / 256
#define TG 3.0f             // speculative threshold
#define BCAP 40             // per-block candidate slots (E~11)
#define CAP_ROW (BPR * BCAP)   // 3920
#define SLOTS_PT 16            // ceil(3920/256)

// ws layout (bytes):
//   cand : u32[ROWS][BPR][BCAP] @ 0       (501760)
//   bcnt : i32[ROWS][BPR]       @ 501760  (12544)   always fully rewritten
//   thr  : f32[ROWS]            @ 514304  (128)
#define OFF_BCNT 501760
#define OFF_THR  514304

// Monotone order-preserving f32 -> u32 key (larger float -> larger key).
__device__ __forceinline__ uint32_t fkey(float x) {
    uint32_t u = __float_as_uint(x);
    return (u & 0x80000000u) ? ~u : (u | 0x80000000u);
}
__device__ __forceinline__ float fkey_inv(uint32_t k) {
    uint32_t u = (k & 0x80000000u) ? (k & 0x7FFFFFFFu) : ~k;
    return __uint_as_float(u);
}

// Pass 1: streaming read; compact values > TG into this block's private slots.
__global__ __launch_bounds__(THREADS) void k_spec(const float* __restrict__ in,
                                                  uint32_t* __restrict__ cand,
                                                  int* __restrict__ bcnt) {
    __shared__ uint32_t lc[BCAP];
    __shared__ int lcnt;
    const int row = blockIdx.x / BPR;
    const int blk = blockIdx.x % BPR;
    if (threadIdx.x == 0) lcnt = 0;
    __syncthreads();
    const float4* p = (const float4*)in + (size_t)row * ROW_LEN4
                      + (size_t)blk * F4_PER_BLOCK + threadIdx.x;
#pragma unroll
    for (int v = 0; v < F4_PER_THREAD; ++v) {
        float4 d = p[v * THREADS];
        if (d.x > TG) { int q = atomicAdd(&lcnt, 1); if (q < BCAP) lc[q] = fkey(d.x); }
        if (d.y > TG) { int q = atomicAdd(&lcnt, 1); if (q < BCAP) lc[q] = fkey(d.y); }
        if (d.z > TG) { int q = atomicAdd(&lcnt, 1); if (q < BCAP) lc[q] = fkey(d.z); }
        if (d.w > TG) { int q = atomicAdd(&lcnt, 1); if (q < BCAP) lc[q] = fkey(d.w); }
    }
    __syncthreads();
    const int c = lcnt;
    if (threadIdx.x == 0) bcnt[row * BPR + blk] = c;  // raw count (overflow detected later)
    const int cc = c < BCAP ? c : BCAP;
    for (int i = threadIdx.x; i < cc; i += THREADS)
        cand[((size_t)row * BPR + blk) * BCAP + i] = lc[i];
}

// Parallel digit pick: h[0..255] histogram -> inclusive suffix scan across the
// 256 threads (Hillis-Steele, 8 steps) -> the unique digit d with
// S[d] >= r > S[d+1]. Uniform control flow; all threads call.
__device__ __forceinline__ void pick_digit(uint32_t* h, int t, int r,
                                           int* sh_sel, int* sh_rank) {
#pragma unroll
    for (int off = 1; off < 256; off <<= 1) {
        uint32_t v = h[t] + ((t + off < 256) ? h[t + off] : 0u);
        __syncthreads();
        h[t] = v;
        __syncthreads();
    }
    const uint32_t Sd = h[t];
    const uint32_t Sd1 = (t < 255) ? h[t + 1] : 0u;
    if ((int)Sd >= r && (int)Sd1 < r) { *sh_sel = t; *sh_rank = r - (int)Sd1; }
    __syncthreads();
}

// Pass 2: per row, exact n-th-largest via 4x8-bit radix select.
// Fast path: candidate slots -> registers, LDS histograms. Fallback path
// (spec overflow / undercount; never taken on this data): full-row radix
// from global memory, same parallel machinery.
__global__ __launch_bounds__(THREADS) void k_sel(const float* __restrict__ in,
                                                 const int* __restrict__ n_ptr,
                                                 const int* __restrict__ bcnt,
                                                 const uint32_t* __restrict__ cand,
                                                 float* __restrict__ thr) {
    __shared__ int lb[BPR];
    __shared__ uint32_t h[256];
    __shared__ int sh_sel, sh_rank, sh_m, sh_bad;
    const int row = blockIdx.x;
    const int t = threadIdx.x;
    const int n = *n_ptr;

    if (t == 0) { sh_m = 0; sh_bad = 0; }
    __syncthreads();
    {
        int lsum = 0, lbad = 0;
        for (int b = t; b < BPR; b += THREADS) {
            const int c = bcnt[row * BPR + b];
            lbad |= (c > BCAP);
            const int cc = c < BCAP ? c : BCAP;
            lb[b] = cc;
            lsum += cc;
        }
        if (lsum) atomicAdd(&sh_m, lsum);
        if (lbad) atomicOr(&sh_bad, 1);
    }
    __syncthreads();
    const int m = sh_m;
    const bool ok = (!sh_bad) && (m >= n) && (n >= 1);

    if (ok) {
        // Coalesced load of the whole slot space into registers; stale slots
        // are masked by validity (lb freshly written by k_spec every call).
        uint32_t key[SLOTS_PT];
        bool val[SLOTS_PT];
#pragma unroll
        for (int j = 0; j < SLOTS_PT; ++j) {
            const int slot = j * THREADS + t;
            uint32_t k = 0; bool v = false;
            if (slot < CAP_ROW) {
                k = cand[(size_t)row * CAP_ROW + slot];
                const int b = slot / BCAP;
                v = (slot - b * BCAP) < lb[b];
            }
            key[j] = k; val[j] = v;
        }
        uint32_t prefix = 0, msk = 0;
        int r = n;
        for (int rd = 0; rd < 4; ++rd) {
            const int shn = 24 - rd * 8;
            h[t] = 0;
            __syncthreads();
#pragma unroll
            for (int j = 0; j < SLOTS_PT; ++j)
                if (val[j] && (key[j] & msk) == prefix)
                    atomicAdd(&h[(key[j] >> shn) & 255u], 1u);
            __syncthreads();
            pick_digit(h, t, r, &sh_sel, &sh_rank);
            prefix |= ((uint32_t)sh_sel) << shn;
            msk |= 255u << shn;
            r = sh_rank;
            __syncthreads();
        }
        if (t == 0) thr[row] = fkey_inv(prefix);
    } else {
        // Exact fallback over the full row (correctness-only path).
        uint32_t prefix = 0, msk = 0;
        int r = (n < 1) ? 1 : n;
        const float4* p = (const float4*)in + (size_t)row * ROW_LEN4;
        for (int rd = 0; rd < 4; ++rd) {
            const int shn = 24 - rd * 8;
            h[t] = 0;
            __syncthreads();
            for (int i = t; i < ROW_LEN4; i += THREADS) {
                const float4 d = p[i];
                uint32_t k;
                k = fkey(d.x); if ((k & msk) == prefix) atomicAdd(&h[(k >> shn) & 255u], 1u);
                k = fkey(d.y); if ((k & msk) == prefix) atomicAdd(&h[(k >> shn) & 255u], 1u);
                k = fkey(d.z); if ((k & msk) == prefix) atomicAdd(&h[(k >> shn) & 255u], 1u);
                k = fkey(d.w); if ((k & msk) == prefix) atomicAdd(&h[(k >> shn) & 255u], 1u);
            }
            __syncthreads();
            pick_digit(h, t, r, &sh_sel, &sh_rank);
            prefix |= ((uint32_t)sh_sel) << shn;
            msk |= 255u << shn;
            r = sh_rank;
            __syncthreads();
        }
        if (t == 0) thr[row] = fkey_inv(prefix);
    }
}

__global__ __launch_bounds__(THREADS) void k_mask(const float* __restrict__ in,
                                                  const float* __restrict__ thr,
                                                  float* __restrict__ out) {
    const int row = blockIdx.x / BPR;
    const int blk = blockIdx.x % BPR;
    const float t = thr[row];
    const size_t base = (size_t)row * ROW_LEN4 + (size_t)blk * F4_PER_BLOCK + threadIdx.x;
    const float4* p = (const float4*)in + base;
    float4* q = (float4*)out + base;
#pragma unroll
    for (int v = 0; v < F4_PER_THREAD; ++v) {
        float4 d = p[v * THREADS];
        d.x = (d.x >= t) ? d.x : 0.0f;
        d.y = (d.y >= t) ? d.y : 0.0f;
        d.z = (d.z >= t) ? d.z : 0.0f;
        d.w = (d.w >= t) ? d.w : 0.0f;
        q[v * THREADS] = d;
    }
}

extern "C" void kernel_launch(void* const* d_in, const int* in_sizes, int n_in,
                              void* d_out, int out_size, void* d_ws, size_t ws_size,
                              hipStream_t stream) {
    const float* in = (const float*)d_in[0];
    const int* n_ptr = (const int*)d_in[1];
    float* out = (float*)d_out;
    char* ws = (char*)d_ws;

    uint32_t* cand = (uint32_t*)ws;
    int* bcnt = (int*)(ws + OFF_BCNT);
    float* thr = (float*)(ws + OFF_THR);

    k_spec<<<ROWS * BPR, THREADS, 0, stream>>>(in, cand, bcnt);
    k_sel<<<ROWS, THREADS, 0, stream>>>(in, n_ptr, bcnt, cand, thr);
    k_mask<<<ROWS * BPR, THREADS, 0, stream>>>(in, thr, out);
}

// Round 5
// 54.462 us; speedup vs baseline: 2.0470x; 1.0108x over previous
//
#include <hip/hip_runtime.h>
#include <stdint.h>

// KeepTopN: inputs (32, 56, 56, 256) f32, n = 48 (k-th largest per row).
// v5: zero-fill output + speculative candidate positions (T=3.0) + fused
// exact radix-select + scatter of the ~48 survivors/row. No full re-read
// for masking. Inline exact fallback (never taken on this data).
#define ROWS 32
#define ROW_LEN 802816      // 56*56*256
#define ROW_LEN4 200704     // ROW_LEN / 4
#define BPR 98              // blocks per row (200704 = 98 * 2048)
#define F4_PER_BLOCK 2048
#define THREADS 256
#define F4_PER_THREAD 8     // 2048 / 256
#define TG 3.0f             // speculative threshold; E[cand/row] ~= 1084
#define BCAP 40             // per-block candidate slots (Poisson mean ~11)
#define CAP_ROW (BPR * BCAP)   // 3920
#define SLOTS_PT 16            // ceil(3920/256)

// ws layout (bytes), ~515 KB (proven size in rounds 3-4):
//   pos  : u32[ROWS][BPR][BCAP] @ 0       (501760)  element index within row
//   bcnt : i32[ROWS][BPR]       @ 501760  (12544)   always fully rewritten
//   thr  : f32[ROWS]            @ 514304  (128)
#define OFF_BCNT 501760
#define OFF_THR  514304

// Monotone order-preserving f32 -> u32 key (larger float -> larger key).
__device__ __forceinline__ uint32_t fkey(float x) {
    uint32_t u = __float_as_uint(x);
    return (u & 0x80000000u) ? ~u : (u | 0x80000000u);
}
__device__ __forceinline__ float fkey_inv(uint32_t k) {
    uint32_t u = (k & 0x80000000u) ? (k & 0x7FFFFFFFu) : ~k;
    return __uint_as_float(u);
}

// Pass 1: streaming read; record POSITIONS of values > TG per block.
__global__ __launch_bounds__(THREADS) void k_spec(const float* __restrict__ in,
                                                  uint32_t* __restrict__ pos,
                                                  int* __restrict__ bcnt) {
    __shared__ uint32_t lp[BCAP];
    __shared__ int lcnt;
    const int row = blockIdx.x / BPR;
    const int blk = blockIdx.x % BPR;
    if (threadIdx.x == 0) lcnt = 0;
    __syncthreads();
    const float4* p = (const float4*)in + (size_t)row * ROW_LEN4
                      + (size_t)blk * F4_PER_BLOCK + threadIdx.x;
#pragma unroll
    for (int v = 0; v < F4_PER_THREAD; ++v) {
        float4 d = p[v * THREADS];
        const uint32_t e = (uint32_t)(blk * F4_PER_BLOCK + v * THREADS + threadIdx.x) * 4u;
        if (d.x > TG) { int q = atomicAdd(&lcnt, 1); if (q < BCAP) lp[q] = e + 0u; }
        if (d.y > TG) { int q = atomicAdd(&lcnt, 1); if (q < BCAP) lp[q] = e + 1u; }
        if (d.z > TG) { int q = atomicAdd(&lcnt, 1); if (q < BCAP) lp[q] = e + 2u; }
        if (d.w > TG) { int q = atomicAdd(&lcnt, 1); if (q < BCAP) lp[q] = e + 3u; }
    }
    __syncthreads();
    const int c = lcnt;
    if (threadIdx.x == 0) bcnt[row * BPR + blk] = c;  // raw (overflow detected later)
    const int cc = c < BCAP ? c : BCAP;
    for (int i = threadIdx.x; i < cc; i += THREADS)
        pos[((size_t)row * BPR + blk) * BCAP + i] = lp[i];
}

// Parallel digit pick: histogram h[256] -> inclusive suffix scan across the
// 256 threads (Hillis-Steele, 8 steps) -> digit d with S[d] >= r > S[d+1].
__device__ __forceinline__ void pick_digit(uint32_t* h, int t, int r,
                                           int* sh_sel, int* sh_rank) {
#pragma unroll
    for (int off = 1; off < 256; off <<= 1) {
        uint32_t v = h[t] + ((t + off < 256) ? h[t + off] : 0u);
        __syncthreads();
        h[t] = v;
        __syncthreads();
    }
    const uint32_t Sd = h[t];
    const uint32_t Sd1 = (t < 255) ? h[t + 1] : 0u;
    if ((int)Sd >= r && (int)Sd1 < r) { *sh_sel = t; *sh_rank = r - (int)Sd1; }
    __syncthreads();
}

// Pass 2: per row: gather candidate keys (input is L3-resident), exact
// 4x8-bit radix select of the n-th largest, then scatter survivors into the
// pre-zeroed output. Fallback (!ok): full-row radix + full-row masked write.
__global__ __launch_bounds__(THREADS) void k_sel(const float* __restrict__ in,
                                                 const int* __restrict__ n_ptr,
                                                 const int* __restrict__ bcnt,
                                                 const uint32_t* __restrict__ pos,
                                                 float* __restrict__ out,
                                                 float* __restrict__ thr) {
    __shared__ int lb[BPR];
    __shared__ uint32_t h[256];
    __shared__ int sh_sel, sh_rank, sh_m, sh_bad;
    const int row = blockIdx.x;
    const int t = threadIdx.x;
    const int n = *n_ptr;
    const float* rin = in + (size_t)row * ROW_LEN;
    float* rout = out + (size_t)row * ROW_LEN;

    if (t == 0) { sh_m = 0; sh_bad = 0; }
    __syncthreads();
    {
        int lsum = 0, lbad = 0;
        for (int b = t; b < BPR; b += THREADS) {
            const int c = bcnt[row * BPR + b];
            lbad |= (c > BCAP);
            const int cc = c < BCAP ? c : BCAP;
            lb[b] = cc;
            lsum += cc;
        }
        if (lsum) atomicAdd(&sh_m, lsum);
        if (lbad) atomicOr(&sh_bad, 1);
    }
    __syncthreads();
    const int m = sh_m;
    const bool ok = (!sh_bad) && (m >= n) && (n >= 1);

    if (ok) {
        // Coalesced slot load + gathered key fetch (L3-hit: input just read).
        uint32_t key[SLOTS_PT];
        uint32_t ps[SLOTS_PT];
        bool val[SLOTS_PT];
#pragma unroll
        for (int j = 0; j < SLOTS_PT; ++j) {
            const int slot = j * THREADS + t;
            uint32_t k = 0, pp = 0; bool v = false;
            if (slot < CAP_ROW) {
                const int b = slot / BCAP;
                v = (slot - b * BCAP) < lb[b];
                if (v) {
                    pp = pos[(size_t)row * CAP_ROW + slot];
                    k = fkey(rin[pp]);
                }
            }
            key[j] = k; ps[j] = pp; val[j] = v;
        }
        uint32_t prefix = 0, msk = 0;
        int r = n;
        for (int rd = 0; rd < 4; ++rd) {
            const int shn = 24 - rd * 8;
            h[t] = 0;
            __syncthreads();
#pragma unroll
            for (int j = 0; j < SLOTS_PT; ++j)
                if (val[j] && (key[j] & msk) == prefix)
                    atomicAdd(&h[(key[j] >> shn) & 255u], 1u);
            __syncthreads();
            pick_digit(h, t, r, &sh_sel, &sh_rank);
            prefix |= ((uint32_t)sh_sel) << shn;
            msk |= 255u << shn;
            r = sh_rank;
            __syncthreads();
        }
        // Scatter survivors (key >= prefix <=> value >= threshold).
#pragma unroll
        for (int j = 0; j < SLOTS_PT; ++j)
            if (val[j] && key[j] >= prefix)
                rout[ps[j]] = fkey_inv(key[j]);
        if (t == 0) thr[row] = fkey_inv(prefix);
    } else {
        // Exact fallback: full-row radix select + full-row masked write.
        uint32_t prefix = 0, msk = 0;
        int r = (n < 1) ? 1 : n;
        const float4* p = (const float4*)rin;
        for (int rd = 0; rd < 4; ++rd) {
            const int shn = 24 - rd * 8;
            h[t] = 0;
            __syncthreads();
            for (int i = t; i < ROW_LEN4; i += THREADS) {
                const float4 d = p[i];
                uint32_t k;
                k = fkey(d.x); if ((k & msk) == prefix) atomicAdd(&h[(k >> shn) & 255u], 1u);
                k = fkey(d.y); if ((k & msk) == prefix) atomicAdd(&h[(k >> shn) & 255u], 1u);
                k = fkey(d.z); if ((k & msk) == prefix) atomicAdd(&h[(k >> shn) & 255u], 1u);
                k = fkey(d.w); if ((k & msk) == prefix) atomicAdd(&h[(k >> shn) & 255u], 1u);
            }
            __syncthreads();
            pick_digit(h, t, r, &sh_sel, &sh_rank);
            prefix |= ((uint32_t)sh_sel) << shn;
            msk |= 255u << shn;
            r = sh_rank;
            __syncthreads();
        }
        const float tf = fkey_inv(prefix);
        float4* q = (float4*)rout;
        for (int i = t; i < ROW_LEN4; i += THREADS) {
            float4 d = p[i];
            d.x = (d.x >= tf) ? d.x : 0.0f;
            d.y = (d.y >= tf) ? d.y : 0.0f;
            d.z = (d.z >= tf) ? d.z : 0.0f;
            d.w = (d.w >= tf) ? d.w : 0.0f;
            q[i] = d;
        }
        if (t == 0) thr[row] = tf;
    }
}

extern "C" void kernel_launch(void* const* d_in, const int* in_sizes, int n_in,
                              void* d_out, int out_size, void* d_ws, size_t ws_size,
                              hipStream_t stream) {
    const float* in = (const float*)d_in[0];
    const int* n_ptr = (const int*)d_in[1];
    float* out = (float*)d_out;
    char* ws = (char*)d_ws;

    uint32_t* pos = (uint32_t*)ws;
    int* bcnt = (int*)(ws + OFF_BCNT);
    float* thr = (float*)(ws + OFF_THR);

    hipMemsetAsync(out, 0, (size_t)out_size * sizeof(float), stream);
    k_spec<<<ROWS * BPR, THREADS, 0, stream>>>(in, pos, bcnt);
    k_sel<<<ROWS, THREADS, 0, stream>>>(in, n_ptr, bcnt, pos, out, thr);
}

// Round 6
// 50.319 us; speedup vs baseline: 2.2155x; 1.0823x over previous
//
#include <hip/hip_runtime.h>
#include <stdint.h>

// KeepTopN: inputs (32, 56, 56, 256) f32, n = 48 (k-th largest per row).
// v6: fused streaming pass (read input + write zeros to out + collect
// candidate positions > TG) -> exact radix-select + scatter survivors.
// Inline exact fallback (never taken on N(0,1) data) keeps correctness
// unconditional.
#define ROWS 32
#define ROW_LEN 802816      // 56*56*256
#define ROW_LEN4 200704     // ROW_LEN / 4
#define BPR 98              // blocks per row (200704 = 98 * 2048)
#define F4_PER_BLOCK 2048
#define THREADS 256
#define F4_PER_THREAD 8     // 2048 / 256
#define TG 3.0f             // speculative threshold; E[cand/row] ~= 1084
#define BCAP 40             // per-block candidate slots (Binomial mean ~11)
#define CAP_ROW (BPR * BCAP)   // 3920
#define SLOTS_PT 16            // ceil(3920/256)

// ws layout (bytes), ~515 KB (proven size in rounds 3-5):
//   pos  : u32[ROWS][BPR][BCAP] @ 0       (501760)  element index within row
//   bcnt : i32[ROWS][BPR]       @ 501760  (12544)   always fully rewritten
//   thr  : f32[ROWS]            @ 514304  (128)
#define OFF_BCNT 501760
#define OFF_THR  514304

// Monotone order-preserving f32 -> u32 key (larger float -> larger key).
__device__ __forceinline__ uint32_t fkey(float x) {
    uint32_t u = __float_as_uint(x);
    return (u & 0x80000000u) ? ~u : (u | 0x80000000u);
}
__device__ __forceinline__ float fkey_inv(uint32_t k) {
    uint32_t u = (k & 0x80000000u) ? (k & 0x7FFFFFFFu) : ~k;
    return __uint_as_float(u);
}

// Pass 1: stream input; write zeros to out at the same offsets; record
// POSITIONS of values > TG per block. One fused 206 MB HBM pass.
__global__ __launch_bounds__(THREADS) void k_spec(const float* __restrict__ in,
                                                  float* __restrict__ out,
                                                  uint32_t* __restrict__ pos,
                                                  int* __restrict__ bcnt) {
    __shared__ uint32_t lp[BCAP];
    __shared__ int lcnt;
    const int row = blockIdx.x / BPR;
    const int blk = blockIdx.x % BPR;
    if (threadIdx.x == 0) lcnt = 0;
    __syncthreads();
    const size_t base = (size_t)row * ROW_LEN4 + (size_t)blk * F4_PER_BLOCK + threadIdx.x;
    const float4* p = (const float4*)in + base;
    float4* q = (float4*)out + base;
    const float4 z = make_float4(0.f, 0.f, 0.f, 0.f);
#pragma unroll
    for (int v = 0; v < F4_PER_THREAD; ++v) {
        float4 d = p[v * THREADS];
        q[v * THREADS] = z;
        const uint32_t e = (uint32_t)(blk * F4_PER_BLOCK + v * THREADS + threadIdx.x) * 4u;
        if (d.x > TG) { int j = atomicAdd(&lcnt, 1); if (j < BCAP) lp[j] = e + 0u; }
        if (d.y > TG) { int j = atomicAdd(&lcnt, 1); if (j < BCAP) lp[j] = e + 1u; }
        if (d.z > TG) { int j = atomicAdd(&lcnt, 1); if (j < BCAP) lp[j] = e + 2u; }
        if (d.w > TG) { int j = atomicAdd(&lcnt, 1); if (j < BCAP) lp[j] = e + 3u; }
    }
    __syncthreads();
    const int c = lcnt;
    if (threadIdx.x == 0) bcnt[row * BPR + blk] = c;  // raw (overflow detected later)
    const int cc = c < BCAP ? c : BCAP;
    for (int i = threadIdx.x; i < cc; i += THREADS)
        pos[((size_t)row * BPR + blk) * BCAP + i] = lp[i];
}

// Parallel digit pick: histogram h[256] -> inclusive suffix scan across the
// 256 threads (Hillis-Steele, 8 steps) -> digit d with S[d] >= r > S[d+1].
__device__ __forceinline__ void pick_digit(uint32_t* h, int t, int r,
                                           int* sh_sel, int* sh_rank) {
#pragma unroll
    for (int off = 1; off < 256; off <<= 1) {
        uint32_t v = h[t] + ((t + off < 256) ? h[t + off] : 0u);
        __syncthreads();
        h[t] = v;
        __syncthreads();
    }
    const uint32_t Sd = h[t];
    const uint32_t Sd1 = (t < 255) ? h[t + 1] : 0u;
    if ((int)Sd >= r && (int)Sd1 < r) { *sh_sel = t; *sh_rank = r - (int)Sd1; }
    __syncthreads();
}

// Pass 2: per row: gather candidate keys (input is L3-resident), exact
// 4x8-bit radix select of the n-th largest, scatter survivors into the
// zeroed output. Fallback (!ok): full-row radix + full-row masked write.
__global__ __launch_bounds__(THREADS) void k_sel(const float* __restrict__ in,
                                                 const int* __restrict__ n_ptr,
                                                 const int* __restrict__ bcnt,
                                                 const uint32_t* __restrict__ pos,
                                                 float* __restrict__ out,
                                                 float* __restrict__ thr) {
    __shared__ int lb[BPR];
    __shared__ uint32_t h[256];
    __shared__ int sh_sel, sh_rank, sh_m, sh_bad;
    const int row = blockIdx.x;
    const int t = threadIdx.x;
    const int n = *n_ptr;
    const float* rin = in + (size_t)row * ROW_LEN;
    float* rout = out + (size_t)row * ROW_LEN;

    if (t == 0) { sh_m = 0; sh_bad = 0; }
    __syncthreads();
    {
        int lsum = 0, lbad = 0;
        for (int b = t; b < BPR; b += THREADS) {
            const int c = bcnt[row * BPR + b];
            lbad |= (c > BCAP);
            const int cc = c < BCAP ? c : BCAP;
            lb[b] = cc;
            lsum += cc;
        }
        if (lsum) atomicAdd(&sh_m, lsum);
        if (lbad) atomicOr(&sh_bad, 1);
    }
    __syncthreads();
    const int m = sh_m;
    const bool ok = (!sh_bad) && (m >= n) && (n >= 1);

    if (ok) {
        // Coalesced slot load + gathered key fetch (L3-hit: input just read).
        uint32_t key[SLOTS_PT];
        uint32_t ps[SLOTS_PT];
        bool val[SLOTS_PT];
#pragma unroll
        for (int j = 0; j < SLOTS_PT; ++j) {
            const int slot = j * THREADS + t;
            uint32_t k = 0, pp = 0; bool v = false;
            if (slot < CAP_ROW) {
                const int b = slot / BCAP;
                v = (slot - b * BCAP) < lb[b];
                if (v) {
                    pp = pos[(size_t)row * CAP_ROW + slot];
                    k = fkey(rin[pp]);
                }
            }
            key[j] = k; ps[j] = pp; val[j] = v;
        }
        uint32_t prefix = 0, msk = 0;
        int r = n;
        for (int rd = 0; rd < 4; ++rd) {
            const int shn = 24 - rd * 8;
            h[t] = 0;
            __syncthreads();
#pragma unroll
            for (int j = 0; j < SLOTS_PT; ++j)
                if (val[j] && (key[j] & msk) == prefix)
                    atomicAdd(&h[(key[j] >> shn) & 255u], 1u);
            __syncthreads();
            pick_digit(h, t, r, &sh_sel, &sh_rank);
            prefix |= ((uint32_t)sh_sel) << shn;
            msk |= 255u << shn;
            r = sh_rank;
            __syncthreads();
        }
        // Scatter survivors (key >= prefix <=> value >= threshold).
#pragma unroll
        for (int j = 0; j < SLOTS_PT; ++j)
            if (val[j] && key[j] >= prefix)
                rout[ps[j]] = fkey_inv(key[j]);
        if (t == 0) thr[row] = fkey_inv(prefix);
    } else {
        // Exact fallback: full-row radix select + full-row masked write.
        uint32_t prefix = 0, msk = 0;
        int r = (n < 1) ? 1 : n;
        const float4* p = (const float4*)rin;
        for (int rd = 0; rd < 4; ++rd) {
            const int shn = 24 - rd * 8;
            h[t] = 0;
            __syncthreads();
            for (int i = t; i < ROW_LEN4; i += THREADS) {
                const float4 d = p[i];
                uint32_t k;
                k = fkey(d.x); if ((k & msk) == prefix) atomicAdd(&h[(k >> shn) & 255u], 1u);
                k = fkey(d.y); if ((k & msk) == prefix) atomicAdd(&h[(k >> shn) & 255u], 1u);
                k = fkey(d.z); if ((k & msk) == prefix) atomicAdd(&h[(k >> shn) & 255u], 1u);
                k = fkey(d.w); if ((k & msk) == prefix) atomicAdd(&h[(k >> shn) & 255u], 1u);
            }
            __syncthreads();
            pick_digit(h, t, r, &sh_sel, &sh_rank);
            prefix |= ((uint32_t)sh_sel) << shn;
            msk |= 255u << shn;
            r = sh_rank;
            __syncthreads();
        }
        const float tf = fkey_inv(prefix);
        float4* q = (float4*)rout;
        for (int i = t; i < ROW_LEN4; i += THREADS) {
            float4 d = p[i];
            d.x = (d.x >= tf) ? d.x : 0.0f;
            d.y = (d.y >= tf) ? d.y : 0.0f;
            d.z = (d.z >= tf) ? d.z : 0.0f;
            d.w = (d.w >= tf) ? d.w : 0.0f;
            q[i] = d;
        }
        if (t == 0) thr[row] = tf;
    }
}

extern "C" void kernel_launch(void* const* d_in, const int* in_sizes, int n_in,
                              void* d_out, int out_size, void* d_ws, size_t ws_size,
                              hipStream_t stream) {
    const float* in = (const float*)d_in[0];
    const int* n_ptr = (const int*)d_in[1];
    float* out = (float*)d_out;
    char* ws = (char*)d_ws;

    uint32_t* pos = (uint32_t*)ws;
    int* bcnt = (int*)(ws + OFF_BCNT);
    float* thr = (float*)(ws + OFF_THR);

    k_spec<<<ROWS * BPR, THREADS, 0, stream>>>(in, out, pos, bcnt);
    k_sel<<<ROWS, THREADS, 0, stream>>>(in, n_ptr, bcnt, pos, out, thr);
}

// Round 8
// 50.181 us; speedup vs baseline: 2.2216x; 1.0028x over previous
//
#include <hip/hip_runtime.h>
#include <stdint.h>

// KeepTopN: inputs (32, 56, 56, 256) f32, n = 48 (k-th largest per row).
// v7b: fused streaming pass restructured for MLP: batch 8 loads -> batch 8
// nontemporal zero-stores (native vector type) -> register-only candidate
// detection with wave-uniform skip (__any). Then exact radix-select +
// scatter survivors. Inline exact fallback (never taken on N(0,1) data)
// keeps correctness unconditional.
#define ROWS 32
#define ROW_LEN 802816      // 56*56*256
#define ROW_LEN4 200704     // ROW_LEN / 4
#define BPR 98              // blocks per row (200704 = 98 * 2048)
#define F4_PER_BLOCK 2048
#define THREADS 256
#define F4_PER_THREAD 8     // 2048 / 256
#define TG 3.0f             // speculative threshold; E[cand/row] ~= 1084
#define BCAP 40             // per-block candidate slots (Binomial mean ~11)
#define CAP_ROW (BPR * BCAP)   // 3920
#define SLOTS_PT 16            // ceil(3920/256)

// ws layout (bytes), ~515 KB:
//   pos  : u32[ROWS][BPR][BCAP] @ 0       (501760)  element index within row
//   bcnt : i32[ROWS][BPR]       @ 501760  (12544)   always fully rewritten
//   thr  : f32[ROWS]            @ 514304  (128)
#define OFF_BCNT 501760
#define OFF_THR  514304

typedef float f32x4 __attribute__((ext_vector_type(4)));  // native clang vector

// Monotone order-preserving f32 -> u32 key (larger float -> larger key).
__device__ __forceinline__ uint32_t fkey(float x) {
    uint32_t u = __float_as_uint(x);
    return (u & 0x80000000u) ? ~u : (u | 0x80000000u);
}
__device__ __forceinline__ float fkey_inv(uint32_t k) {
    uint32_t u = (k & 0x80000000u) ? (k & 0x7FFFFFFFu) : ~k;
    return __uint_as_float(u);
}

// Pass 1: stream input; write zeros to out at the same offsets; record
// POSITIONS of values > TG per block. One fused 206 MB pass, MLP-friendly.
__global__ __launch_bounds__(THREADS) void k_spec(const float* __restrict__ in,
                                                  float* __restrict__ out,
                                                  uint32_t* __restrict__ pos,
                                                  int* __restrict__ bcnt) {
    __shared__ uint32_t lp[BCAP];
    __shared__ int lcnt;
    const int row = blockIdx.x / BPR;
    const int blk = blockIdx.x % BPR;
    if (threadIdx.x == 0) lcnt = 0;
    __syncthreads();
    const size_t base = (size_t)row * ROW_LEN4 + (size_t)blk * F4_PER_BLOCK + threadIdx.x;
    const float4* p = (const float4*)in + base;
    f32x4* q = (f32x4*)out + base;
    const f32x4 z = {0.f, 0.f, 0.f, 0.f};

    // Phase 1: all loads in flight.
    float4 d[F4_PER_THREAD];
#pragma unroll
    for (int v = 0; v < F4_PER_THREAD; ++v) d[v] = p[v * THREADS];
    // Phase 2: zero the output (nontemporal: write-once, never re-read here).
#pragma unroll
    for (int v = 0; v < F4_PER_THREAD; ++v)
        __builtin_nontemporal_store(z, q + v * THREADS);
    // Phase 3: register-only detection; wave-uniform skip of the rare path.
#pragma unroll
    for (int v = 0; v < F4_PER_THREAD; ++v) {
        const float mx = fmaxf(fmaxf(d[v].x, d[v].y), fmaxf(d[v].z, d[v].w));
        if (__any(mx > TG)) {
            const uint32_t e = (uint32_t)(blk * F4_PER_BLOCK + v * THREADS + threadIdx.x) * 4u;
            if (d[v].x > TG) { int j = atomicAdd(&lcnt, 1); if (j < BCAP) lp[j] = e + 0u; }
            if (d[v].y > TG) { int j = atomicAdd(&lcnt, 1); if (j < BCAP) lp[j] = e + 1u; }
            if (d[v].z > TG) { int j = atomicAdd(&lcnt, 1); if (j < BCAP) lp[j] = e + 2u; }
            if (d[v].w > TG) { int j = atomicAdd(&lcnt, 1); if (j < BCAP) lp[j] = e + 3u; }
        }
    }
    __syncthreads();
    const int c = lcnt;
    if (threadIdx.x == 0) bcnt[row * BPR + blk] = c;  // raw (overflow detected later)
    const int cc = c < BCAP ? c : BCAP;
    for (int i = threadIdx.x; i < cc; i += THREADS)
        pos[((size_t)row * BPR + blk) * BCAP + i] = lp[i];
}

// Parallel digit pick: histogram h[256] -> inclusive suffix scan across the
// 256 threads (Hillis-Steele, 8 steps) -> digit d with S[d] >= r > S[d+1].
__device__ __forceinline__ void pick_digit(uint32_t* h, int t, int r,
                                           int* sh_sel, int* sh_rank) {
#pragma unroll
    for (int off = 1; off < 256; off <<= 1) {
        uint32_t v = h[t] + ((t + off < 256) ? h[t + off] : 0u);
        __syncthreads();
        h[t] = v;
        __syncthreads();
    }
    const uint32_t Sd = h[t];
    const uint32_t Sd1 = (t < 255) ? h[t + 1] : 0u;
    if ((int)Sd >= r && (int)Sd1 < r) { *sh_sel = t; *sh_rank = r - (int)Sd1; }
    __syncthreads();
}

// Pass 2: per row: gather candidate keys (input is L2/L3-resident), exact
// 4x8-bit radix select of the n-th largest, scatter survivors into the
// zeroed output. Fallback (!ok): full-row radix + full-row masked write.
__global__ __launch_bounds__(THREADS) void k_sel(const float* __restrict__ in,
                                                 const int* __restrict__ n_ptr,
                                                 const int* __restrict__ bcnt,
                                                 const uint32_t* __restrict__ pos,
                                                 float* __restrict__ out,
                                                 float* __restrict__ thr) {
    __shared__ int lb[BPR];
    __shared__ uint32_t h[256];
    __shared__ int sh_sel, sh_rank, sh_m, sh_bad;
    const int row = blockIdx.x;
    const int t = threadIdx.x;
    const int n = *n_ptr;
    const float* rin = in + (size_t)row * ROW_LEN;
    float* rout = out + (size_t)row * ROW_LEN;

    if (t == 0) { sh_m = 0; sh_bad = 0; }
    __syncthreads();
    {
        int lsum = 0, lbad = 0;
        for (int b = t; b < BPR; b += THREADS) {
            const int c = bcnt[row * BPR + b];
            lbad |= (c > BCAP);
            const int cc = c < BCAP ? c : BCAP;
            lb[b] = cc;
            lsum += cc;
        }
        if (lsum) atomicAdd(&sh_m, lsum);
        if (lbad) atomicOr(&sh_bad, 1);
    }
    __syncthreads();
    const int m = sh_m;
    const bool ok = (!sh_bad) && (m >= n) && (n >= 1);

    if (ok) {
        // Coalesced slot load + gathered key fetch (cache-hit: just written).
        uint32_t key[SLOTS_PT];
        uint32_t ps[SLOTS_PT];
        bool val[SLOTS_PT];
#pragma unroll
        for (int j = 0; j < SLOTS_PT; ++j) {
            const int slot = j * THREADS + t;
            uint32_t k = 0, pp = 0; bool v = false;
            if (slot < CAP_ROW) {
                const int b = slot / BCAP;
                v = (slot - b * BCAP) < lb[b];
                if (v) {
                    pp = pos[(size_t)row * CAP_ROW + slot];
                    k = fkey(rin[pp]);
                }
            }
            key[j] = k; ps[j] = pp; val[j] = v;
        }
        uint32_t prefix = 0, msk = 0;
        int r = n;
        for (int rd = 0; rd < 4; ++rd) {
            const int shn = 24 - rd * 8;
            h[t] = 0;
            __syncthreads();
#pragma unroll
            for (int j = 0; j < SLOTS_PT; ++j)
                if (val[j] && (key[j] & msk) == prefix)
                    atomicAdd(&h[(key[j] >> shn) & 255u], 1u);
            __syncthreads();
            pick_digit(h, t, r, &sh_sel, &sh_rank);
            prefix |= ((uint32_t)sh_sel) << shn;
            msk |= 255u << shn;
            r = sh_rank;
            __syncthreads();
        }
        // Scatter survivors (key >= prefix <=> value >= threshold).
#pragma unroll
        for (int j = 0; j < SLOTS_PT; ++j)
            if (val[j] && key[j] >= prefix)
                rout[ps[j]] = fkey_inv(key[j]);
        if (t == 0) thr[row] = fkey_inv(prefix);
    } else {
        // Exact fallback: full-row radix select + full-row masked write.
        uint32_t prefix = 0, msk = 0;
        int r = (n < 1) ? 1 : n;
        const float4* p = (const float4*)rin;
        for (int rd = 0; rd < 4; ++rd) {
            const int shn = 24 - rd * 8;
            h[t] = 0;
            __syncthreads();
            for (int i = t; i < ROW_LEN4; i += THREADS) {
                const float4 d = p[i];
                uint32_t k;
                k = fkey(d.x); if ((k & msk) == prefix) atomicAdd(&h[(k >> shn) & 255u], 1u);
                k = fkey(d.y); if ((k & msk) == prefix) atomicAdd(&h[(k >> shn) & 255u], 1u);
                k = fkey(d.z); if ((k & msk) == prefix) atomicAdd(&h[(k >> shn) & 255u], 1u);
                k = fkey(d.w); if ((k & msk) == prefix) atomicAdd(&h[(k >> shn) & 255u], 1u);
            }
            __syncthreads();
            pick_digit(h, t, r, &sh_sel, &sh_rank);
            prefix |= ((uint32_t)sh_sel) << shn;
            msk |= 255u << shn;
            r = sh_rank;
            __syncthreads();
        }
        const float tf = fkey_inv(prefix);
        float4* q = (float4*)rout;
        for (int i = t; i < ROW_LEN4; i += THREADS) {
            float4 d = p[i];
            d.x = (d.x >= tf) ? d.x : 0.0f;
            d.y = (d.y >= tf) ? d.y : 0.0f;
            d.z = (d.z >= tf) ? d.z : 0.0f;
            d.w = (d.w >= tf) ? d.w : 0.0f;
            q[i] = d;
        }
        if (t == 0) thr[row] = tf;
    }
}

extern "C" void kernel_launch(void* const* d_in, const int* in_sizes, int n_in,
                              void* d_out, int out_size, void* d_ws, size_t ws_size,
                              hipStream_t stream) {
    const float* in = (const float*)d_in[0];
    const int* n_ptr = (const int*)d_in[1];
    float* out = (float*)d_out;
    char* ws = (char*)d_ws;

    uint32_t* pos = (uint32_t*)ws;
    int* bcnt = (int*)(ws + OFF_BCNT);
    float* thr = (float*)(ws + OFF_THR);

    k_spec<<<ROWS * BPR, THREADS, 0, stream>>>(in, out, pos, bcnt);
    k_sel<<<ROWS, THREADS, 0, stream>>>(in, n_ptr, bcnt, pos, out, thr);
}